// Round 6
// baseline (442.462 us; speedup 1.0000x reference)
//
#include <hip/hip_runtime.h>
#include <hip/hip_fp16.h>

#define N_NODES 50000
#define N_EDGES 800000

typedef _Float16 half8 __attribute__((ext_vector_type(8)));
typedef _Float16 f16x4 __attribute__((ext_vector_type(4)));
typedef float floatx4 __attribute__((ext_vector_type(4)));

// ---------------------------------------------------------------------------
// setup (strided): row_ptr lower_bound; packed edges (src|dst<<16, both <2^16);
// lw0 cast; lw1/lw2 fold (64x256 fp32) -> planar K=192 fp16 [o, ch*64+f],
// ch {0:h0+h1, 1:a2, 2:a3}.
// ---------------------------------------------------------------------------
__global__ __launch_bounds__(256) void setup_kernel(const int* __restrict__ src,
                                                    const int* __restrict__ dst,
                                                    int* __restrict__ row_ptr,
                                                    unsigned* __restrict__ packed,
                                                    const float* __restrict__ lw0,
                                                    const float* __restrict__ lw1,
                                                    const float* __restrict__ lw2,
                                                    _Float16* __restrict__ w0p,
                                                    _Float16* __restrict__ w1p,
                                                    _Float16* __restrict__ w2p) {
    const int gid = blockIdx.x * 256 + threadIdx.x;
    const int gstride = gridDim.x * 256;
    for (int idx = gid; idx <= N_NODES; idx += gstride) {
        int lo = 0, hi = N_EDGES;
        while (lo < hi) {
            int mid = (lo + hi) >> 1;
            if (src[mid] < idx) lo = mid + 1; else hi = mid;
        }
        row_ptr[idx] = lo;
    }
    for (int idx = gid; idx < N_EDGES; idx += gstride)
        packed[idx] = (unsigned)src[idx] | ((unsigned)dst[idx] << 16);
    for (int idx = gid; idx < 64 * 128; idx += gstride) w0p[idx] = (_Float16)lw0[idx];
    for (int idx = gid; idx < 64 * 192; idx += gstride) {
        int o = idx / 192, r = idx % 192;
        int ch = r >> 6, f = r & 63;
        float v1, v2;
        if (ch == 0) {
            v1 = lw1[o * 256 + f * 4 + 0] + lw1[o * 256 + f * 4 + 1];
            v2 = lw2[o * 256 + f * 4 + 0] + lw2[o * 256 + f * 4 + 1];
        } else if (ch == 1) {
            v1 = lw1[o * 256 + f * 4 + 2];
            v2 = lw2[o * 256 + f * 4 + 2];
        } else {
            v1 = lw1[o * 256 + f * 4 + 3];
            v2 = lw2[o * 256 + f * 4 + 3];
        }
        w1p[idx] = (_Float16)v1;
        w2p[idx] = (_Float16)v2;
    }
}

// ---------------------------------------------------------------------------
// lin via MFMA 16x16x32 f16 (layout verified R8). 4 waves, 16 rows x 64 cols
// per wave. TIn=float folds the x cast in. Stores E = exp(score).
// ---------------------------------------------------------------------------
template <typename TIn, int K>
__global__ __launch_bounds__(256) void lin_kernel(const TIn* __restrict__ in,
                                                  const _Float16* __restrict__ w,
                                                  const float* __restrict__ b,
                                                  const float* __restrict__ aw,
                                                  _Float16* __restrict__ h,
                                                  float2* __restrict__ s, int n) {
    const int t = threadIdx.x;
    const int l = t & 63;
    const int wv = t >> 6;
    const int arow = l & 15;
    const int kg = l >> 4;
    const long rowbase = (long)blockIdx.x * 64 + wv * 16;
    long arow_g = rowbase + arow;
    if (arow_g >= n) arow_g = n - 1;

    floatx4 acc[4] = {};

    for (int kc = 0; kc < K; kc += 32) {
        const int ks = kc + kg * 8;
        half8 a;
        if (sizeof(TIn) == 4) {
            const TIn* ap = in + arow_g * K + ks;
            #pragma unroll
            for (int j = 0; j < 8; ++j) a[j] = (_Float16)ap[j];
        } else {
            a = *(const half8*)((const _Float16*)in + arow_g * K + ks);
        }
        #pragma unroll
        for (int ct = 0; ct < 4; ++ct) {
            half8 bb = *(const half8*)(w + (long)(ct * 16 + arow) * K + ks);
            acc[ct] = __builtin_amdgcn_mfma_f32_16x16x32_f16(a, bb, acc[ct], 0, 0, 0);
        }
    }

    const int c = l & 15;
    const int rq = l >> 4;
    float bias[4], a2c[4], a3c[4];
    #pragma unroll
    for (int ct = 0; ct < 4; ++ct) {
        int col = ct * 16 + c;
        bias[ct] = b[col];
        a2c[ct] = aw[2 * 128 + col] + aw[2 * 128 + 64 + col];
        a3c[ct] = aw[3 * 128 + col] + aw[3 * 128 + 64 + col];
    }
    #pragma unroll
    for (int r = 0; r < 4; ++r) {
        long row = rowbase + rq * 4 + r;
        bool ok = row < n;
        float q2 = 0.f, q3 = 0.f;
        _Float16 hv[4];
        #pragma unroll
        for (int ct = 0; ct < 4; ++ct) {
            float u = acc[ct][r] + bias[ct];
            u = u > 0.f ? u : 0.2f * u;
            q2 += u * a2c[ct];
            q3 += u * a3c[ct];
            hv[ct] = (_Float16)u;
        }
        if (ok) {
            #pragma unroll
            for (int ct = 0; ct < 4; ++ct) h[row * 64 + ct * 16 + c] = hv[ct];
        }
        #pragma unroll
        for (int o = 1; o < 16; o <<= 1) {
            q2 += __shfl_xor(q2, o);
            q3 += __shfl_xor(q3, o);
        }
        if (c == 0 && ok) s[row] = make_float2(__expf(q2), __expf(q3));
    }
}

// ---------------------------------------------------------------------------
// R17 layer kernel: EDGE-BALANCED aggregation + fused next-lin.
// Block = 16 nodes, W = their edge count. 16 quarters get EQUAL runs of
// ~W/16 consecutive edges (edges sorted by src). Per edge: ONE packed u32
// load gives src+dst (no bpermute chain), f16x4 h-gather + float2 E
// (quarter-broadcast). Registers accumulate am/a2/a3/S while src unchanged;
// on change (quarter-uniform predicate, short unrolled body) flush via LDS
// atomicAdd (ds_add_f32) into accum[16][3][64]. Outer loop bound ceil(W/16)
// is BLOCK-uniform -> no inter-quarter PC divergence. Removes the old
// max-of-4-degree padding (~1.55x slots) and the dst->bpermute round trip.
// Then: normalize (thread=node x f-quad) -> g_lds -> proven MFMA phase B.
// LDS ~19KB -> 8 blocks/CU.
// ---------------------------------------------------------------------------
template <int FINAL>
__global__ __launch_bounds__(256) void layer_kernel(const _Float16* __restrict__ hfeat,
                                                    const float2* __restrict__ E,
                                                    const unsigned* __restrict__ packed,
                                                    const int* __restrict__ row_ptr,
                                                    const _Float16* __restrict__ w,
                                                    const float* __restrict__ b,
                                                    const float* __restrict__ aw,
                                                    _Float16* __restrict__ h_out,
                                                    float2* __restrict__ s_out,
                                                    float* __restrict__ out_f) {
    __shared__ float accum[16][3][64];     // 12 KB, ch {0:am, 1:a2, 2:a3}
    __shared__ float Ssum[16][2];
    __shared__ int rp[17];
    __shared__ _Float16 g_lds[16][200];
    __shared__ float2 spart[4][16];

    const int t = threadIdx.x;
    const int l = t & 63;
    const int wv = t >> 6;
    const int q = l >> 4;
    const int fl = l & 15;
    const int base = blockIdx.x * 16;
    const int qg = wv * 4 + q;             // quarter id 0..15

    if (t < 17) rp[t] = row_ptr[base + t];
    {
        float* ap = (float*)accum;         // 3072 floats = 12 per thread
        #pragma unroll
        for (int z = 0; z < 12; ++z) ap[t + z * 256] = 0.f;
        if (t < 32) ((float*)Ssum)[t] = 0.f;
    }
    __syncthreads();

    const int e_lo = rp[0];
    const int W = rp[16] - e_lo;

    if (W > 0) {
        const int rs = e_lo + (int)(((unsigned)W * (unsigned)qg) >> 4);
        const int re = e_lo + (int)(((unsigned)W * (unsigned)(qg + 1)) >> 4);
        const int Lmax = (W + 15) >> 4;    // block-uniform outer bound
        // clamp target for invalid/empty lanes, always inside this block
        const int ecl = (re > e_lo) ? re - 1 : e_lo;

        int cn = (int)(packed[(rs < re) ? rs : ecl] & 0xffffu);  // quarter-uniform
        float am[4] = {}, a2[4] = {}, a3[4] = {};
        float S2 = 0.f, S3 = 0.f;

        for (int off = 0; off < Lmax; off += 4) {
            unsigned pk[4]; float vm[4];
            #pragma unroll
            for (int g = 0; g < 4; ++g) {
                int ee = rs + off + g;
                int ec = ee < re ? ee : ecl;
                pk[g] = packed[ec];        // 16 lanes same addr: broadcast
                vm[g] = ee < re ? 1.f : 0.f;
            }
            f16x4 hv[4]; float2 Ev[4];
            #pragma unroll
            for (int g = 0; g < 4; ++g) {
                const int dg = (int)(pk[g] >> 16);
                hv[g] = *(const f16x4*)(hfeat + (long)dg * 64 + fl * 4);
                Ev[g] = E[dg];             // quarter-broadcast
            }
            #pragma unroll
            for (int g = 0; g < 4; ++g) {
                const int sg = (int)(pk[g] & 0xffffu);
                if (vm[g] > 0.f && sg != cn) {   // quarter-uniform predicate
                    const int cnl = cn - base;
                    #pragma unroll
                    for (int k = 0; k < 4; ++k) {
                        atomicAdd(&accum[cnl][0][fl * 4 + k], am[k]);
                        atomicAdd(&accum[cnl][1][fl * 4 + k], a2[k]);
                        atomicAdd(&accum[cnl][2][fl * 4 + k], a3[k]);
                        am[k] = 0.f; a2[k] = 0.f; a3[k] = 0.f;
                    }
                    if (fl == 0) {
                        atomicAdd(&Ssum[cnl][0], S2);
                        atomicAdd(&Ssum[cnl][1], S3);
                    }
                    S2 = 0.f; S3 = 0.f;
                    cn = sg;
                }
                const float e2 = vm[g] * Ev[g].x, e3 = vm[g] * Ev[g].y;
                S2 += e2; S3 += e3;
                #pragma unroll
                for (int k = 0; k < 4; ++k) {
                    const float hf = (float)hv[g][k];
                    am[k] += vm[g] * hf;
                    a2[k] += e2 * hf;
                    a3[k] += e3 * hf;
                }
            }
        }
        {   // final flush
            const int cnl = cn - base;
            #pragma unroll
            for (int k = 0; k < 4; ++k) {
                atomicAdd(&accum[cnl][0][fl * 4 + k], am[k]);
                atomicAdd(&accum[cnl][1][fl * 4 + k], a2[k]);
                atomicAdd(&accum[cnl][2][fl * 4 + k], a3[k]);
            }
            if (fl == 0) {
                atomicAdd(&Ssum[cnl][0], S2);
                atomicAdd(&Ssum[cnl][1], S3);
            }
        }
    }
    __syncthreads();

    // normalize: thread = node (t>>4) x feature-quad (t&15)
    const int nl2 = t >> 4;
    const int f2 = t & 15;
    const int degn = rp[nl2 + 1] - rp[nl2];
    const float idg = degn > 0 ? 1.f / (float)degn : 0.f;
    const float iS2 = degn > 0 ? 1.f / Ssum[nl2][0] : 0.f;
    const float iS3 = degn > 0 ? 1.f / Ssum[nl2][1] : 0.f;

    if (FINAL) {
        floatx4 o;
        #pragma unroll
        for (int k = 0; k < 4; ++k) {
            const int f = f2 * 4 + k;
            o[k] = fmaxf(0.5f * idg * accum[nl2][0][f] +
                         0.25f * (accum[nl2][1][f] * iS2 + accum[nl2][2][f] * iS3), 0.f);
        }
        *(floatx4*)(out_f + (long)(base + nl2) * 64 + f2 * 4) = o;
        return;
    }

    {
        f16x4 o0, o1, o2;
        #pragma unroll
        for (int k = 0; k < 4; ++k) {
            const int f = f2 * 4 + k;
            o0[k] = (_Float16)fmaxf(accum[nl2][0][f] * idg, 0.f);
            o1[k] = (_Float16)fmaxf(accum[nl2][1][f] * iS2, 0.f);
            o2[k] = (_Float16)fmaxf(accum[nl2][2][f] * iS3, 0.f);
        }
        *(f16x4*)(&g_lds[nl2][f2 * 4])       = o0;
        *(f16x4*)(&g_lds[nl2][64 + f2 * 4])  = o1;
        *(f16x4*)(&g_lds[nl2][128 + f2 * 4]) = o2;
    }
    __syncthreads();

    // Phase B (proven): lin for these 16 rows. Wave wv = cols wv*16..+15.
    floatx4 acc = {};
    #pragma unroll
    for (int kc = 0; kc < 192; kc += 32) {
        const int ks = kc + q * 8;
        half8 a = *(const half8*)(&g_lds[fl][ks]);
        half8 bb = *(const half8*)(w + (long)(wv * 16 + fl) * 192 + ks);
        acc = __builtin_amdgcn_mfma_f32_16x16x32_f16(a, bb, acc, 0, 0, 0);
    }

    const int col = wv * 16 + fl;
    const float bias = b[col];
    const float a2c = aw[2 * 128 + col] + aw[2 * 128 + 64 + col];
    const float a3c = aw[3 * 128 + col] + aw[3 * 128 + 64 + col];
    #pragma unroll
    for (int r = 0; r < 4; ++r) {
        const int row = q * 4 + r;
        float u = acc[r] + bias;
        u = u > 0.f ? u : 0.2f * u;
        h_out[(long)(base + row) * 64 + col] = (_Float16)u;
        float q2 = u * a2c, q3 = u * a3c;
        #pragma unroll
        for (int o = 1; o < 16; o <<= 1) {
            q2 += __shfl_xor(q2, o);
            q3 += __shfl_xor(q3, o);
        }
        if (fl == 0) spart[wv][row] = make_float2(q2, q3);
    }
    __syncthreads();
    if (t < 16) {
        const float2 p0 = spart[0][t], p1 = spart[1][t], p2 = spart[2][t], p3 = spart[3][t];
        s_out[base + t] = make_float2(__expf(p0.x + p1.x + p2.x + p3.x),
                                      __expf(p0.y + p1.y + p2.y + p3.y));
    }
}

// ---------------------------------------------------------------------------
extern "C" void kernel_launch(void* const* d_in, const int* in_sizes, int n_in,
                              void* d_out, int out_size, void* d_ws, size_t ws_size,
                              hipStream_t stream) {
    const float* x = (const float*)d_in[0];
    const float* lw0 = (const float*)d_in[1];
    const float* lb0 = (const float*)d_in[2];
    const float* aw0 = (const float*)d_in[3];
    const float* lw1 = (const float*)d_in[5];
    const float* lb1 = (const float*)d_in[6];
    const float* aw1 = (const float*)d_in[7];
    const float* lw2 = (const float*)d_in[9];
    const float* lb2 = (const float*)d_in[10];
    const float* aw2 = (const float*)d_in[11];
    const int* src = (const int*)d_in[13];
    const int* dst = (const int*)d_in[14];
    float* out = (float*)d_out;

    const int N = N_NODES;

    // ws layout: hA,hB: N*64 f16 | sA,sB: N float2 | w0p 64*128 f16
    //            | w1p,w2p 64*192 f16 | row_ptr N+1 int | packed N_EDGES u32
    _Float16* hA = (_Float16*)d_ws;
    _Float16* hB = hA + (size_t)N * 64;
    float2* sA = (float2*)(hB + (size_t)N * 64);
    float2* sB = sA + N;
    _Float16* w0p = (_Float16*)(sB + N);
    _Float16* w1p = w0p + 64 * 128;
    _Float16* w2p = w1p + 64 * 192;
    int* row_ptr = (int*)(w2p + 64 * 192);
    unsigned* packed = (unsigned*)(row_ptr + N + 1);

    const int lin_grid = (N + 63) / 64;      // 782
    const int layer_grid = N / 16;           // 3125

    setup_kernel<<<196, 256, 0, stream>>>(src, dst, row_ptr, packed,
                                          lw0, lw1, lw2, w0p, w1p, w2p);
    lin_kernel<float, 128><<<lin_grid, 256, 0, stream>>>(x, w0p, lb0, aw0, hA, sA, N);
    layer_kernel<0><<<layer_grid, 256, 0, stream>>>(hA, sA, packed, row_ptr,
                                                    w1p, lb1, aw1, hB, sB, out);
    layer_kernel<0><<<layer_grid, 256, 0, stream>>>(hB, sB, packed, row_ptr,
                                                    w2p, lb2, aw2, hA, sA, out);
    layer_kernel<1><<<layer_grid, 256, 0, stream>>>(hA, sA, packed, row_ptr,
                                                    w2p, lb2, aw2, hB, sB, out);
}

// Round 7
// 233.073 us; speedup vs baseline: 1.8984x; 1.8984x over previous
//
#include <hip/hip_runtime.h>
#include <hip/hip_fp16.h>

#define N_NODES 50000
#define N_EDGES 800000
#define BUCKET_SPLIT 25000

typedef _Float16 half8 __attribute__((ext_vector_type(8)));
typedef _Float16 f16x4 __attribute__((ext_vector_type(4)));
typedef float floatx4 __attribute__((ext_vector_type(4)));

// ---------------------------------------------------------------------------
// setup (strided): row_ptr lower_bound; dstp = per-node dst values partitioned
// into [dst<25000 | dst>=25000] with row_mid the split point (each bucket's
// h-slice = 3.2MB, fits a 4MB per-XCD L2); lw0 cast; lw1/lw2 fold (64x256
// fp32) -> planar K=192 fp16 [o, ch*64+f], ch {0:h0+h1, 1:a2, 2:a3}.
// Partition recomputes node bounds via binary search (no intra-kernel
// dependency on row_ptr[] written by other threads).
// ---------------------------------------------------------------------------
__global__ __launch_bounds__(256) void setup_kernel(const int* __restrict__ src,
                                                    const int* __restrict__ dst,
                                                    int* __restrict__ row_ptr,
                                                    int* __restrict__ row_mid,
                                                    int* __restrict__ dstp,
                                                    const float* __restrict__ lw0,
                                                    const float* __restrict__ lw1,
                                                    const float* __restrict__ lw2,
                                                    _Float16* __restrict__ w0p,
                                                    _Float16* __restrict__ w1p,
                                                    _Float16* __restrict__ w2p) {
    const int gid = blockIdx.x * 256 + threadIdx.x;
    const int gstride = gridDim.x * 256;
    for (int idx = gid; idx <= N_NODES; idx += gstride) {
        int lo = 0, hi = N_EDGES;
        while (lo < hi) {
            int mid = (lo + hi) >> 1;
            if (src[mid] < idx) lo = mid + 1; else hi = mid;
        }
        row_ptr[idx] = lo;
    }
    for (int i = gid; i < N_NODES; i += gstride) {
        int lo = 0, hi = N_EDGES;
        while (lo < hi) { int m = (lo + hi) >> 1; if (src[m] < i) lo = m + 1; else hi = m; }
        int lo1 = lo, hi1 = N_EDGES;
        while (lo1 < hi1) { int m = (lo1 + hi1) >> 1; if (src[m] < i + 1) lo1 = m + 1; else hi1 = m; }
        int c = lo;
        for (int e = lo; e < lo1; ++e) { int d = dst[e]; if (d < BUCKET_SPLIT) dstp[c++] = d; }
        row_mid[i] = c;
        for (int e = lo; e < lo1; ++e) { int d = dst[e]; if (d >= BUCKET_SPLIT) dstp[c++] = d; }
    }
    for (int idx = gid; idx < 64 * 128; idx += gstride) w0p[idx] = (_Float16)lw0[idx];
    for (int idx = gid; idx < 64 * 192; idx += gstride) {
        int o = idx / 192, r = idx % 192;
        int ch = r >> 6, f = r & 63;
        float v1, v2;
        if (ch == 0) {
            v1 = lw1[o * 256 + f * 4 + 0] + lw1[o * 256 + f * 4 + 1];
            v2 = lw2[o * 256 + f * 4 + 0] + lw2[o * 256 + f * 4 + 1];
        } else if (ch == 1) {
            v1 = lw1[o * 256 + f * 4 + 2];
            v2 = lw2[o * 256 + f * 4 + 2];
        } else {
            v1 = lw1[o * 256 + f * 4 + 3];
            v2 = lw2[o * 256 + f * 4 + 3];
        }
        w1p[idx] = (_Float16)v1;
        w2p[idx] = (_Float16)v2;
    }
}

// ---------------------------------------------------------------------------
// lin via MFMA 16x16x32 f16 (layout verified R8). 4 waves, 16 rows x 64 cols
// per wave. TIn=float folds the x cast in. Stores E = exp(score).
// ---------------------------------------------------------------------------
template <typename TIn, int K>
__global__ __launch_bounds__(256) void lin_kernel(const TIn* __restrict__ in,
                                                  const _Float16* __restrict__ w,
                                                  const float* __restrict__ b,
                                                  const float* __restrict__ aw,
                                                  _Float16* __restrict__ h,
                                                  float2* __restrict__ s, int n) {
    const int t = threadIdx.x;
    const int l = t & 63;
    const int wv = t >> 6;
    const int arow = l & 15;
    const int kg = l >> 4;
    const long rowbase = (long)blockIdx.x * 64 + wv * 16;
    long arow_g = rowbase + arow;
    if (arow_g >= n) arow_g = n - 1;

    floatx4 acc[4] = {};

    for (int kc = 0; kc < K; kc += 32) {
        const int ks = kc + kg * 8;
        half8 a;
        if (sizeof(TIn) == 4) {
            const TIn* ap = in + arow_g * K + ks;
            #pragma unroll
            for (int j = 0; j < 8; ++j) a[j] = (_Float16)ap[j];
        } else {
            a = *(const half8*)((const _Float16*)in + arow_g * K + ks);
        }
        #pragma unroll
        for (int ct = 0; ct < 4; ++ct) {
            half8 bb = *(const half8*)(w + (long)(ct * 16 + arow) * K + ks);
            acc[ct] = __builtin_amdgcn_mfma_f32_16x16x32_f16(a, bb, acc[ct], 0, 0, 0);
        }
    }

    const int c = l & 15;
    const int rq = l >> 4;
    float bias[4], a2c[4], a3c[4];
    #pragma unroll
    for (int ct = 0; ct < 4; ++ct) {
        int col = ct * 16 + c;
        bias[ct] = b[col];
        a2c[ct] = aw[2 * 128 + col] + aw[2 * 128 + 64 + col];
        a3c[ct] = aw[3 * 128 + col] + aw[3 * 128 + 64 + col];
    }
    #pragma unroll
    for (int r = 0; r < 4; ++r) {
        long row = rowbase + rq * 4 + r;
        bool ok = row < n;
        float q2 = 0.f, q3 = 0.f;
        _Float16 hv[4];
        #pragma unroll
        for (int ct = 0; ct < 4; ++ct) {
            float u = acc[ct][r] + bias[ct];
            u = u > 0.f ? u : 0.2f * u;
            q2 += u * a2c[ct];
            q3 += u * a3c[ct];
            hv[ct] = (_Float16)u;
        }
        if (ok) {
            #pragma unroll
            for (int ct = 0; ct < 4; ++ct) h[row * 64 + ct * 16 + c] = hv[ct];
        }
        #pragma unroll
        for (int o = 1; o < 16; o <<= 1) {
            q2 += __shfl_xor(q2, o);
            q3 += __shfl_xor(q3, o);
        }
        if (c == 0 && ok) s[row] = make_float2(__expf(q2), __expf(q3));
    }
}

// ---------------------------------------------------------------------------
// R18 layer kernel: R2's PROVEN fused structure (quarter-per-node agg +
// LDS-staged MFMA next-lin), with ONE change: the agg runs in TWO PASSES
// over the dst-partitioned edge list (bucket 0: dst<25000, bucket 1: rest),
// pass order flipped by blockIdx parity (blocks round-robin XCDs, so each
// XCD's concurrently-resident blocks share a ~3.2MB gather working set that
// fits the 4MB per-XCD L2). Accumulators persist across passes (sums are
// order-independent). R17's atomic/edge-balanced scheme reverted: it
// compiled to 32 VGPR and serialized the gather pipeline (4x regression).
// ---------------------------------------------------------------------------
template <int FINAL>
__global__ __launch_bounds__(256) void layer_kernel(const _Float16* __restrict__ hfeat,
                                                    const float2* __restrict__ E,
                                                    const int* __restrict__ dstp,
                                                    const int* __restrict__ row_ptr,
                                                    const int* __restrict__ row_mid,
                                                    const _Float16* __restrict__ w,
                                                    const float* __restrict__ b,
                                                    const float* __restrict__ aw,
                                                    _Float16* __restrict__ h_out,
                                                    float2* __restrict__ s_out,
                                                    float* __restrict__ out_f) {
    __shared__ _Float16 g_lds[16][200];
    __shared__ float2 spart[4][16];

    const int t = threadIdx.x;
    const int l = t & 63;
    const int wv = t >> 6;
    const int q = l >> 4;      // phase A: node slot | phase B: k-group
    const int fl = l & 15;     // phase A: feature quad | phase B: row/col lane
    const int base = blockIdx.x * 16;
    const int i = base + wv * 4 + q;           // N_NODES % 16 == 0 -> valid

    const int r0 = row_ptr[i], r1 = row_ptr[i + 1], rm = row_mid[i];
    const int deg = r1 - r0;

    float am[4] = {}, a2[4] = {}, a3[4] = {};
    float S2 = 0.f, S3 = 0.f;

    #pragma unroll
    for (int pp = 0; pp < 2; ++pp) {
        const int p = pp ^ (int)(blockIdx.x & 1);   // XCD-staggered bucket order
        const int plo = p ? rm : r0;
        const int phi = p ? r1 : rm;
        const int pdeg = phi - plo;
        int md = pdeg;
        md = max(md, __shfl_xor(md, 16));
        md = max(md, __shfl_xor(md, 32));           // wave-uniform max sub-degree
        const int psafe = pdeg > 0 ? phi - 1 : 0;   // clamp for padded lanes

        for (int c0 = 0; c0 < md; c0 += 16) {
            const int dl = dstp[min(plo + c0 + fl, psafe)];  // 16 dst ids / quarter
            const int jn = min(16, md - c0);                 // uniform inner bound
            for (int j = 0; j < jn; j += 4) {
                int dg[4]; float vm[4];
                #pragma unroll
                for (int g = 0; g < 4; ++g) {
                    const int sl = j + g;                    // <= 15 always
                    dg[g] = __shfl(dl, (q << 4) | sl);       // broadcast in-quarter
                    vm[g] = (c0 + sl < pdeg) ? 1.f : 0.f;
                }
                f16x4 hv[4]; float2 Ev[4];
                #pragma unroll
                for (int g = 0; g < 4; ++g) {
                    hv[g] = *(const f16x4*)(hfeat + (long)dg[g] * 64 + fl * 4);
                    Ev[g] = E[dg[g]];                        // quarter-uniform bcast
                }
                #pragma unroll
                for (int g = 0; g < 4; ++g) {
                    const float e2 = vm[g] * Ev[g].x, e3 = vm[g] * Ev[g].y;
                    S2 += e2; S3 += e3;
                    #pragma unroll
                    for (int k = 0; k < 4; ++k) {
                        const float hf = (float)hv[g][k];
                        am[k] += vm[g] * hf;
                        a2[k] += e2 * hf;
                        a3[k] += e3 * hf;
                    }
                }
            }
        }
    }

    const float inv_deg = deg > 0 ? 1.f / (float)deg : 0.f;
    const float i2 = deg > 0 ? 1.f / S2 : 0.f;
    const float i3 = deg > 0 ? 1.f / S3 : 0.f;

    if (FINAL) {
        floatx4 o;
        #pragma unroll
        for (int k = 0; k < 4; ++k)
            o[k] = fmaxf(0.5f * inv_deg * am[k] + 0.25f * (a2[k] * i2 + a3[k] * i3), 0.f);
        *(floatx4*)(out_f + (long)i * 64 + fl * 4) = o;
        return;
    }

    // g row into LDS (all 16 lanes of the quarter write their own quads)
    {
        const int nl = wv * 4 + q;
        f16x4 o0, o1, o2;
        #pragma unroll
        for (int k = 0; k < 4; ++k) {
            o0[k] = (_Float16)fmaxf(am[k] * inv_deg, 0.f);
            o1[k] = (_Float16)fmaxf(a2[k] * i2, 0.f);
            o2[k] = (_Float16)fmaxf(a3[k] * i3, 0.f);
        }
        *(f16x4*)(&g_lds[nl][fl * 4])       = o0;
        *(f16x4*)(&g_lds[nl][64 + fl * 4])  = o1;
        *(f16x4*)(&g_lds[nl][128 + fl * 4]) = o2;
    }
    __syncthreads();

    // Phase B (proven): lin for these 16 rows. Wave wv = cols wv*16..+15.
    floatx4 acc = {};
    #pragma unroll
    for (int kc = 0; kc < 192; kc += 32) {
        const int ks = kc + q * 8;
        half8 a = *(const half8*)(&g_lds[fl][ks]);
        half8 bb = *(const half8*)(w + (long)(wv * 16 + fl) * 192 + ks);
        acc = __builtin_amdgcn_mfma_f32_16x16x32_f16(a, bb, acc, 0, 0, 0);
    }

    const int col = wv * 16 + fl;
    const float bias = b[col];
    const float a2c = aw[2 * 128 + col] + aw[2 * 128 + 64 + col];
    const float a3c = aw[3 * 128 + col] + aw[3 * 128 + 64 + col];
    #pragma unroll
    for (int r = 0; r < 4; ++r) {
        const int row = q * 4 + r;
        float u = acc[r] + bias;
        u = u > 0.f ? u : 0.2f * u;
        h_out[(long)(base + row) * 64 + col] = (_Float16)u;
        float q2 = u * a2c, q3 = u * a3c;
        #pragma unroll
        for (int o = 1; o < 16; o <<= 1) {
            q2 += __shfl_xor(q2, o);
            q3 += __shfl_xor(q3, o);
        }
        if (fl == 0) spart[wv][row] = make_float2(q2, q3);
    }
    __syncthreads();
    if (t < 16) {
        const float2 p0 = spart[0][t], p1 = spart[1][t], p2 = spart[2][t], p3 = spart[3][t];
        s_out[base + t] = make_float2(__expf(p0.x + p1.x + p2.x + p3.x),
                                      __expf(p0.y + p1.y + p2.y + p3.y));
    }
}

// ---------------------------------------------------------------------------
extern "C" void kernel_launch(void* const* d_in, const int* in_sizes, int n_in,
                              void* d_out, int out_size, void* d_ws, size_t ws_size,
                              hipStream_t stream) {
    const float* x = (const float*)d_in[0];
    const float* lw0 = (const float*)d_in[1];
    const float* lb0 = (const float*)d_in[2];
    const float* aw0 = (const float*)d_in[3];
    const float* lw1 = (const float*)d_in[5];
    const float* lb1 = (const float*)d_in[6];
    const float* aw1 = (const float*)d_in[7];
    const float* lw2 = (const float*)d_in[9];
    const float* lb2 = (const float*)d_in[10];
    const float* aw2 = (const float*)d_in[11];
    const int* src = (const int*)d_in[13];
    const int* dst = (const int*)d_in[14];
    float* out = (float*)d_out;

    const int N = N_NODES;

    // ws layout: hA,hB: N*64 f16 | sA,sB: N float2 | w0p 64*128 f16
    //            | w1p,w2p 64*192 f16 | row_ptr N+1 | row_mid N | dstp N_EDGES
    _Float16* hA = (_Float16*)d_ws;
    _Float16* hB = hA + (size_t)N * 64;
    float2* sA = (float2*)(hB + (size_t)N * 64);
    float2* sB = sA + N;
    _Float16* w0p = (_Float16*)(sB + N);
    _Float16* w1p = w0p + 64 * 128;
    _Float16* w2p = w1p + 64 * 192;
    int* row_ptr = (int*)(w2p + 64 * 192);
    int* row_mid = row_ptr + N + 1;
    int* dstp = row_mid + N;

    const int lin_grid = (N + 63) / 64;      // 782
    const int layer_grid = N / 16;           // 3125

    setup_kernel<<<196, 256, 0, stream>>>(src, dst, row_ptr, row_mid, dstp,
                                          lw0, lw1, lw2, w0p, w1p, w2p);
    lin_kernel<float, 128><<<lin_grid, 256, 0, stream>>>(x, w0p, lb0, aw0, hA, sA, N);
    layer_kernel<0><<<layer_grid, 256, 0, stream>>>(hA, sA, dstp, row_ptr, row_mid,
                                                    w1p, lb1, aw1, hB, sB, out);
    layer_kernel<0><<<layer_grid, 256, 0, stream>>>(hB, sB, dstp, row_ptr, row_mid,
                                                    w2p, lb2, aw2, hA, sA, out);
    layer_kernel<1><<<layer_grid, 256, 0, stream>>>(hA, sA, dstp, row_ptr, row_mid,
                                                    w2p, lb2, aw2, hB, sB, out);
}